// Round 8
// baseline (150.377 us; speedup 1.0000x reference)
//
#include <hip/hip_runtime.h>
#include <hip/hip_bf16.h>

// Problem constants (fixed by setup_inputs): B=64, T=1024, C=768, CK=64, R=256
#define BB 64
#define TT 1024
#define CC 768
#define CKK 64
#define SS 512   // T/2
#define RR 256
#define TOUT 768 // R + S
#define ASTRIDE 68  // 64 + 4 pad: 16B-aligned, stride mod 32 = 4 -> 2-way max
#define NSCORE (BB * 8)       // 512 score blocks
#define NSORT  BB             // 64 sorter blocks (spin on done[b])
#define NCOPY  (BB * SS / 4)  // 8192 copy blocks (wave per row, 4 rows/block)
#define HALFROWS (BB * TOUT / 2)  // 24576

typedef float v4f __attribute__((ext_vector_type(4)));

// ---------------------------------------------------------------------------
// Kernel 1 (fused by block range), one dispatch:
//  [0, NSCORE): register-tiled max-GEMM scores[s,d]=dot(k[2s],k[2d+1]);
//    XCD-clustered (blockIdx%8 == batch%8). On completion: release-fence +
//    atomicAdd(done[batch]).
//  [NSCORE, NSCORE+NSORT): per-batch sorter. Spins (s_sleep) until done[b]==8,
//    acquire; then 256-thread bitonic sort of 512 keys (2 elems/thread;
//    j=256 in-register, j=64/128 via LDS, j<=32 shfl), builds unm_idx +
//    per-dst CSR descriptors. Runs entirely under the copy blocks' HBM time.
//  [NSCORE+NSORT, ...): dst-base copy out[b][R+d] = x[b][2d+1] (NT float4).
// ---------------------------------------------------------------------------
__global__ __launch_bounds__(256) void fused_kernel(
    const float* __restrict__ k, const float* __restrict__ x,
    float* __restrict__ out, unsigned long long* __restrict__ nodekey,
    int* __restrict__ done, int* __restrict__ unm_idx,
    int* __restrict__ dstinfo, int* __restrict__ csr) {
  const int bid = blockIdx.x;
  const int t = threadIdx.x;

  __shared__ __align__(16) char smem[52224];

  if (bid >= NSCORE + NSORT) {
    // ---------------- dst-base copy path ----------------
    const int w = t >> 6, l = t & 63;
    const int rowg = (bid - NSCORE - NSORT) * 4 + w;
    const int b = rowg >> 9;
    const int d = rowg & 511;
    const v4f* s = (const v4f*)(x + ((size_t)b * TT + 2 * d + 1) * CC);
    v4f* dst = (v4f*)(out + ((size_t)b * TOUT + RR + d) * CC);
    v4f a0 = __builtin_nontemporal_load(s + l);
    v4f a1 = __builtin_nontemporal_load(s + l + 64);
    v4f a2 = __builtin_nontemporal_load(s + l + 128);
    __builtin_nontemporal_store(a0, dst + l);
    __builtin_nontemporal_store(a1, dst + l + 64);
    __builtin_nontemporal_store(a2, dst + l + 128);
    return;
  }

  if (bid >= NSCORE) {
    // ---------------- sorter path (one block per batch) ----------------
    const int b = bid - NSCORE;
    unsigned long long* keyS = (unsigned long long*)smem;     // 512*8
    int* nodeidx = (int*)(smem + 4096);                       // 512*4
    int* headS   = (int*)(smem + 6144);                       // 512*4
    int* nxtS    = (int*)(smem + 8192);                       // 256*4
    int* eS      = (int*)(smem + 9216);                       // 256*4
    int* wsum    = (int*)(smem + 10240);                      // 8*4

    if (t == 0) {
      while (__hip_atomic_load(&done[b], __ATOMIC_ACQUIRE,
                               __HIP_MEMORY_SCOPE_AGENT) < 8)
        __builtin_amdgcn_s_sleep(8);
    }
    __syncthreads();  // publish acquire to whole block

    const int lane = t & 63, w = t >> 6;
    // thread t holds elements i0=t (slot0) and i1=t+256 (slot1)
    unsigned long long my0, my1;
    {
      unsigned long long nk = nodekey[b * SS + t];
      unsigned int mapped;
      int nidx;
      if (t == 0) {  // scores[:,0,:]=NEG_INF -> max=-1e30, argmax=0
        mapped = ~__float_as_uint(-1e30f);
        nidx = 0;
      } else {
        mapped = (unsigned int)(nk >> 32);
        nidx = SS - 1 - (int)(nk & 0xffffffffu);
      }
      nodeidx[t] = nidx;
      my0 = ((unsigned long long)(~mapped) << 32) | (unsigned int)t;
    }
    {
      unsigned long long nk = nodekey[b * SS + t + 256];
      unsigned int mapped = (unsigned int)(nk >> 32);
      nodeidx[t + 256] = SS - 1 - (int)(nk & 0xffffffffu);
      my1 = ((unsigned long long)(~mapped) << 32) | (unsigned int)(t + 256);
    }
    headS[t] = -1;
    headS[t + 256] = -1;

    for (int kk = 2; kk <= SS; kk <<= 1) {
      for (int j = kk >> 1; j > 0; j >>= 1) {
        unsigned long long p0, p1;
        if (j == 256) {
          p0 = my1; p1 = my0;
        } else if (j >= 64) {
          __syncthreads();
          keyS[t] = my0; keyS[t + 256] = my1;
          __syncthreads();
          p0 = keyS[t ^ j]; p1 = keyS[(t ^ j) + 256];
        } else {
          p0 = __shfl_xor(my0, j);
          p1 = __shfl_xor(my1, j);
        }
        {
          bool tm = (((t & kk) == 0) == (((t & j) == 0)));
          my0 = ((p0 < my0) == tm) ? p0 : my0;
        }
        {
          int i1 = t + 256;
          bool tm = (((i1 & kk) == 0) == (((i1 & j) == 0)));
          my1 = ((p1 < my1) == tm) ? p1 : my1;
        }
      }
    }

    // positions: slot0 = rank t (src set), slot1 = rank t+256 (unm set)
    int esrc = (int)(my0 & 0xffffffffu);
    unm_idx[b * RR + t] = (int)(my1 & 0xffffffffu);
    eS[t] = esrc;
    __syncthreads();
    int dsrc = nodeidx[esrc];
    nxtS[t] = atomicExch(&headS[dsrc], t);
    __syncthreads();

    // per-dst chain counting (d0 = t, d1 = t+256)
    int cnt0 = 0;
    for (int it = headS[t]; it >= 0; it = nxtS[it]) ++cnt0;
    int cnt1 = 0;
    for (int it = headS[t + 256]; it >= 0; it = nxtS[it]) ++cnt1;

    // inclusive scans (wave shfl + cross-wave serial combine)
    int v0 = cnt0, v1 = cnt1;
#pragma unroll
    for (int o = 1; o < 64; o <<= 1) {
      int n0 = __shfl_up(v0, o), n1 = __shfl_up(v1, o);
      if (lane >= o) { v0 += n0; v1 += n1; }
    }
    if (lane == 63) { wsum[w] = v0; wsum[4 + w] = v1; }
    __syncthreads();
    if (t == 0) {
      int run = 0;
      for (int q = 0; q < 8; ++q) { int tmp = wsum[q]; wsum[q] = run; run += tmp; }
    }
    __syncthreads();
    int off0 = wsum[w] + v0 - cnt0;
    int off1 = wsum[4 + w] + v1 - cnt1;

    int j = 0;
    for (int it = headS[t]; it >= 0; it = nxtS[it]) csr[b * RR + off0 + (j++)] = eS[it];
    int e00 = (cnt0 > 0) ? eS[headS[t]] : 0;
    dstinfo[b * SS + t] = cnt0 | (e00 << 9) | (off0 << 18);
    j = 0;
    for (int it = headS[t + 256]; it >= 0; it = nxtS[it]) csr[b * RR + off1 + (j++)] = eS[it];
    int e01 = (cnt1 > 0) ? eS[headS[t + 256]] : 0;
    dstinfo[b * SS + t + 256] = cnt1 | (e01 << 9) | (off1 << 18);
    return;
  }

  // ---------------- score path ----------------
  // batch-clustered remap: bid = (b/8)*64 + rt*8 + (b%8) -> bid%8 = b%8
  const int low3 = bid & 7;
  const int g = bid >> 3;
  const int rt = g & 7;
  const int b = (g >> 3) * 8 + low3;
  const int tx = t & 15, ty = t >> 4;

  float* As = (float*)smem;             // 64*68*4  = 17408
  float* Bs = (float*)(smem + 17408);   // 128*68*4 = 34816

#pragma unroll
  for (int l = 0; l < 4; ++l) {
    int f = t + l * 256;
    int row = f >> 4, c4 = f & 15;
    float4 va = ((const float4*)(k + ((size_t)b * TT + 2 * (rt * 64 + row)) * CKK))[c4];
    *(float4*)(&As[row * ASTRIDE + c4 * 4]) = va;
  }

  unsigned long long rkey[4];
#pragma unroll
  for (int i = 0; i < 4; ++i) rkey[i] = 0ull;

  for (int ct = 0; ct < 4; ++ct) {
    __syncthreads();
#pragma unroll
    for (int l = 0; l < 8; ++l) {
      int f = t + l * 256;
      int row = f >> 4, c4 = f & 15;
      float4 vb = ((const float4*)(k + ((size_t)b * TT + 2 * (ct * 128 + row) + 1) * CKK))[c4];
      *(float4*)(&Bs[row * ASTRIDE + c4 * 4]) = vb;
    }
    __syncthreads();

    float acc[4][8];
#pragma unroll
    for (int i = 0; i < 4; ++i)
#pragma unroll
      for (int j = 0; j < 8; ++j) acc[i][j] = 0.f;

    for (int k4 = 0; k4 < 16; ++k4) {
      float4 av[4], bv[8];
#pragma unroll
      for (int i = 0; i < 4; ++i)
        av[i] = *(const float4*)(&As[(ty + 16 * i) * ASTRIDE + k4 * 4]);
#pragma unroll
      for (int j = 0; j < 8; ++j)
        bv[j] = *(const float4*)(&Bs[(tx + 16 * j) * ASTRIDE + k4 * 4]);
#pragma unroll
      for (int i = 0; i < 4; ++i)
#pragma unroll
        for (int j = 0; j < 8; ++j) {
          acc[i][j] += av[i].x * bv[j].x;
          acc[i][j] += av[i].y * bv[j].y;
          acc[i][j] += av[i].z * bv[j].z;
          acc[i][j] += av[i].w * bv[j].w;
        }
    }

#pragma unroll
    for (int i = 0; i < 4; ++i) {
      float mx = acc[i][0];
      int mj = 0;
#pragma unroll
      for (int j = 1; j < 8; ++j)
        if (acc[i][j] > mx) { mx = acc[i][j]; mj = j; }  // asc d: > keeps min d
      int d = ct * 128 + tx + 16 * mj;
      unsigned int u = __float_as_uint(mx);
      unsigned int mapped = (u & 0x80000000u) ? ~u : (u | 0x80000000u);
      unsigned long long key =
          ((unsigned long long)mapped << 32) | (unsigned int)(SS - 1 - d);
      if (key > rkey[i]) rkey[i] = key;
    }
  }

#pragma unroll
  for (int i = 0; i < 4; ++i) {
#pragma unroll
    for (int off = 1; off < 16; off <<= 1) {
      unsigned long long o = __shfl_xor(rkey[i], off);
      if (o > rkey[i]) rkey[i] = o;
    }
  }
  if (tx == 0) {
#pragma unroll
    for (int i = 0; i < 4; ++i)
      nodekey[b * SS + rt * 64 + ty + 16 * i] = rkey[i];
  }
  __syncthreads();  // all block stores issued & drained (vmcnt before barrier)
  if (t == 0) {
    __threadfence();  // agent-scope release of this block's nodekey stores
    __hip_atomic_fetch_add(&done[b], 1, __ATOMIC_RELEASE,
                           __HIP_MEMORY_SCOPE_AGENT);
  }
}

// ---------------------------------------------------------------------------
// Kernel 2: remainder assembly. Each wave processes TWO distant rows; all
// bulk traffic non-temporal (x even rows read exactly once: unm ∪ chain).
//  rows [0,R):   out = x[2*unm_idx[p]]
//  rows [R,768): if cnt>0: out = out_base + x[2*e0] + extra CSR rows
// ---------------------------------------------------------------------------
__device__ __forceinline__ void process_row(
    const float* __restrict__ x, const int* __restrict__ unm_idx,
    const int* __restrict__ dstinfo, const int* __restrict__ csr,
    float* __restrict__ out, int pg, int l) {
  const int b = pg / TOUT;
  const int p = pg % TOUT;
  v4f* dst = (v4f*)(out + ((size_t)b * TOUT + p) * CC);

  if (p < RR) {
    int srow = 2 * __builtin_amdgcn_readfirstlane(unm_idx[b * RR + p]);
    const v4f* s = (const v4f*)(x + ((size_t)b * TT + srow) * CC);
    v4f a0 = __builtin_nontemporal_load(s + l);
    v4f a1 = __builtin_nontemporal_load(s + l + 64);
    v4f a2 = __builtin_nontemporal_load(s + l + 128);
    __builtin_nontemporal_store(a0, dst + l);
    __builtin_nontemporal_store(a1, dst + l + 64);
    __builtin_nontemporal_store(a2, dst + l + 128);
  } else {
    int d = p - RR;
    int info = __builtin_amdgcn_readfirstlane(dstinfo[b * SS + d]);
    int cnt = info & 511;
    if (cnt == 0) return;  // base row already correct from K1
    int e0 = (info >> 9) & 511;
    int off = (info >> 18) & 511;
    const v4f* s0 = (const v4f*)(out + ((size_t)b * TOUT + p) * CC);  // base
    const v4f* s1 = (const v4f*)(x + ((size_t)b * TT + 2 * e0) * CC);
    v4f a0 = __builtin_nontemporal_load(s0 + l);
    v4f a1 = __builtin_nontemporal_load(s0 + l + 64);
    v4f a2 = __builtin_nontemporal_load(s0 + l + 128);
    v4f v0 = __builtin_nontemporal_load(s1 + l);
    v4f v1 = __builtin_nontemporal_load(s1 + l + 64);
    v4f v2 = __builtin_nontemporal_load(s1 + l + 128);
    a0 += v0; a1 += v1; a2 += v2;
    for (int j = 1; j < cnt; ++j) {
      int e = __builtin_amdgcn_readfirstlane(csr[b * RR + off + j]);
      const v4f* s = (const v4f*)(x + ((size_t)b * TT + 2 * e) * CC);
      v4f u0 = __builtin_nontemporal_load(s + l);
      v4f u1 = __builtin_nontemporal_load(s + l + 64);
      v4f u2 = __builtin_nontemporal_load(s + l + 128);
      a0 += u0; a1 += u1; a2 += u2;
    }
    __builtin_nontemporal_store(a0, dst + l);
    __builtin_nontemporal_store(a1, dst + l + 64);
    __builtin_nontemporal_store(a2, dst + l + 128);
  }
}

__global__ __launch_bounds__(256) void gather_kernel(
    const float* __restrict__ x, const int* __restrict__ unm_idx,
    const int* __restrict__ dstinfo, const int* __restrict__ csr,
    float* __restrict__ out) {
  const int w = threadIdx.x >> 6;
  const int l = threadIdx.x & 63;
  const int r1 = blockIdx.x * 4 + w;
  process_row(x, unm_idx, dstinfo, csr, out, r1, l);
  process_row(x, unm_idx, dstinfo, csr, out, r1 + HALFROWS, l);
}

extern "C" void kernel_launch(void* const* d_in, const int* in_sizes, int n_in,
                              void* d_out, int out_size, void* d_ws, size_t ws_size,
                              hipStream_t stream) {
  const float* x = (const float*)d_in[0];
  const float* k = (const float*)d_in[1];
  float* out = (float*)d_out;

  char* ws = (char*)d_ws;
  unsigned long long* nodekey = (unsigned long long*)(ws);  // 64*512*8 = 262144
  int* unm_idx = (int*)(ws + 262144);                       // 64*256*4 =  65536
  int* dstinfo = (int*)(ws + 327680);                       // 64*512*4 = 131072
  int* csr     = (int*)(ws + 458752);                       // 64*256*4 =  65536
  int* done    = (int*)(ws + 524288);                       // 64*4     =    256
                                                            // total 524544 B

  hipMemsetAsync(done, 0, BB * sizeof(int), stream);
  fused_kernel<<<NSCORE + NSORT + NCOPY, 256, 0, stream>>>(
      k, x, out, nodekey, done, unm_idx, dstinfo, csr);
  gather_kernel<<<HALFROWS / 4, 256, 0, stream>>>(x, unm_idx, dstinfo, csr, out);
}